// Round 12
// baseline (179.213 us; speedup 1.0000x reference)
//
#include <hip/hip_runtime.h>

#define N_NODES 50000
#define IN_DIM 64
#define OUT_DIM 128
#define N_EDGES 800000

#define NB 196                       // blocks == buckets of 256 dst nodes
#define ES 4082                      // ceil(N_EDGES / NB) edges per block slice
#define WLDS 136                     // padded bf16 row stride (bank step 4 -> 2-way, free)
#define FIXSCALE 1048576.0f          // 2^20 fixed point (|sum| < 2^31 guaranteed)
#define INVFIX (1.0f / 1048576.0f)

typedef __attribute__((ext_vector_type(8))) short bf16x8;
typedef __attribute__((ext_vector_type(4))) float f32x4;

__device__ __forceinline__ unsigned short f2bf(float f) {
    unsigned u = __float_as_uint(f);
    unsigned r = u + 0x7FFFu + ((u >> 16) & 1u);   // round-to-nearest-even
    return (unsigned short)(r >> 16);
}

// acc swizzle: feature f of node nd at acc[nd*64 + (f ^ ((nd&7)<<3))]
// gather write: banks = permutation of lanes -> 2-way (free); mean read: 8-bank spread.
__device__ __forceinline__ int SW(int nd, int f) { return (nd << 6) + (f ^ ((nd & 7) << 3)); }

// device-scope generation spin barrier; all NB blocks guaranteed co-resident
// (1 block/CU, NB=196 <= 256 CUs).
__device__ __forceinline__ void gbar(int* cnt, int* gen) {
    __syncthreads();
    if (threadIdx.x == 0) {
        __threadfence();
        int g = __hip_atomic_load(gen, __ATOMIC_RELAXED, __HIP_MEMORY_SCOPE_AGENT);
        int a = __hip_atomic_fetch_add(cnt, 1, __ATOMIC_ACQ_REL, __HIP_MEMORY_SCOPE_AGENT);
        if (a == NB - 1) {
            __hip_atomic_store(cnt, 0, __ATOMIC_RELAXED, __HIP_MEMORY_SCOPE_AGENT);
            __hip_atomic_fetch_add(gen, 1, __ATOMIC_RELEASE, __HIP_MEMORY_SCOPE_AGENT);
        } else {
            while (__hip_atomic_load(gen, __ATOMIC_ACQUIRE, __HIP_MEMORY_SCOPE_AGENT) == g)
                __builtin_amdgcn_s_sleep(2);
        }
        __threadfence();
    }
    __syncthreads();
}

__global__ __launch_bounds__(1024, 4) void sage_mega(
    const float* __restrict__ x, const int* __restrict__ ei,
    const float* __restrict__ Wl, const float* __restrict__ bl,
    const float* __restrict__ Wr,
    int* __restrict__ bar,          // [0]=cnt, [1]=gen (memset to 0 per call)
    int* __restrict__ cnt_mat,      // [NB][NB]
    int* __restrict__ tot,          // [NB]
    unsigned* __restrict__ ebuf,    // [N_EDGES]
    unsigned short* __restrict__ xh,// [N_NODES*64] bf16
    float* __restrict__ out)
{
    __shared__ int acc[256 * 64];                 // 64 KB
    __shared__ unsigned short wlds[128 * WLDS];   // 34.8 KB
    __shared__ int histcur[NB];
    __shared__ int rowpref[NB];
    __shared__ int dcnt[256];
    __shared__ float bls[128];
    __shared__ int bsbe[2];

    const int t = threadIdx.x, b = blockIdx.x;
    const int lane = t & 63, w = t >> 6;          // 16 waves
    const int* dsti = ei + N_EDGES;
    int* cnt_b = bar + 0;
    int* gen_b = bar + 1;

    // ---------------- P1: W->wlds, bias, x slice -> bf16, dst histogram ----------------
    for (int idx = t; idx < 128 * 32; idx += 1024) {     // 128 rows x 32 quads
        int o = idx >> 5, c4 = idx & 31;
        const float* srcw = (c4 < 16) ? (Wr + o * 64 + c4 * 4)
                                      : (Wl + o * 64 + (c4 - 16) * 4);
        float4 v = *(const float4*)srcw;
        ushort4 h4;
        h4.x = f2bf(v.x); h4.y = f2bf(v.y); h4.z = f2bf(v.z); h4.w = f2bf(v.w);
        *(ushort4*)(&wlds[o * WLDS + c4 * 4]) = h4;
    }
    if (t < 128) bls[t] = bl[t];

    const int r0 = b * 256;
    for (int idx = t; idx < 256 * 16; idx += 1024) {     // 256 rows x 16 quads
        int row = idx >> 4, c4 = idx & 15;
        int g = r0 + row;
        if (g < N_NODES) {
            float4 v = ((const float4*)x)[g * 16 + c4];
            ushort4 h4;
            h4.x = f2bf(v.x); h4.y = f2bf(v.y); h4.z = f2bf(v.z); h4.w = f2bf(v.w);
            ((ushort4*)xh)[g * 16 + c4] = h4;
        }
    }

    for (int i = t; i < NB; i += 1024) histcur[i] = 0;
    __syncthreads();
    const int es = b * ES;
    const int ee = min(es + ES, N_EDGES);
    for (int e = es + t; e < ee; e += 1024)
        atomicAdd(&histcur[dsti[e] >> 8], 1);
    __syncthreads();
    for (int j = t; j < NB; j += 1024) cnt_mat[j * NB + b] = histcur[j];

    gbar(cnt_b, gen_b);   // #1: cnt_mat complete

    // ---------------- P2a: row b prefix + total ----------------
    if (t < 64) {
        int carry = 0;
#pragma unroll
        for (int c = 0; c < 4; ++c) {
            int i = c * 64 + t;
            int v = (i < NB) ? cnt_mat[b * NB + i] : 0;
            int incl = v;
#pragma unroll
            for (int d = 1; d < 64; d <<= 1) {
                int u = __shfl_up(incl, d, 64);
                if (t >= d) incl += u;
            }
            if (i < NB) rowpref[i] = carry + incl - v;
            carry += __shfl(incl, 63, 64);
        }
        if (t == 0) tot[b] = carry;
    }

    gbar(cnt_b, gen_b);   // #2: all totals ready

    // ---------------- P2b: bucket start (scan of tot at index b) + cursors ----------------
    if (t < 64) {
        int carry = 0;
#pragma unroll
        for (int c = 0; c < 4; ++c) {
            int i = c * 64 + t;
            int v = (i < NB) ? tot[i] : 0;
            int incl = v;
#pragma unroll
            for (int d = 1; d < 64; d <<= 1) {
                int u = __shfl_up(incl, d, 64);
                if (t >= d) incl += u;
            }
            if (i == b) bsbe[0] = carry + incl - v;
            carry += __shfl(incl, 63, 64);
        }
    }
    __syncthreads();
    for (int j = t; j < NB; j += 1024) cnt_mat[b * NB + j] = bsbe[0] + rowpref[j];
    if (t == 0) bsbe[1] = bsbe[0] + tot[b];

    gbar(cnt_b, gen_b);   // #3: all cursors ready

    // ---------------- P3: place edges; also zero acc/dcnt for P4 ----------------
    for (int j = t; j < NB; j += 1024) histcur[j] = cnt_mat[j * NB + b];
#pragma unroll
    for (int i = 0; i < 16; ++i) acc[i * 1024 + t] = 0;
    if (t < 256) dcnt[t] = 0;
    __syncthreads();
    for (int e = es + t; e < ee; e += 1024) {
        int src = ei[e], dst = dsti[e];
        int pos = atomicAdd(&histcur[dst >> 8], 1);
        ebuf[pos] = (unsigned)src | ((unsigned)(dst & 255) << 16);
    }

    gbar(cnt_b, gen_b);   // #4: ebuf complete everywhere

    // ---------------- P4: edge-parallel gather (int fixed-point LDS) ----------------
    const int bs = bsbe[0], be = bsbe[1];

    for (int e = bs + t; e < be; e += 1024)
        atomicAdd(&dcnt[(ebuf[e] >> 16) & 255], 1);

    for (int e0 = bs + w * 64; e0 < be; e0 += 1024) {
        int m = be - e0; if (m > 64) m = 64;
        unsigned pv = (lane < m) ? ebuf[e0 + lane] : 0u;
        for (int k = 0; k < m; k += 16) {
            unsigned p[16]; int fx[16];
#pragma unroll
            for (int u = 0; u < 16; ++u) p[u] = __shfl(pv, k + u, 64);
#pragma unroll
            for (int u = 0; u < 16; ++u) {
                unsigned short hv = xh[(size_t)(p[u] & 0xFFFFu) * IN_DIM + lane];
                fx[u] = __float2int_rn(__uint_as_float((unsigned)hv << 16) * FIXSCALE);
            }
#pragma unroll
            for (int u = 0; u < 16; ++u) {
                if (k + u < m) {
                    int nd = (p[u] >> 16) & 255;
                    atomicAdd(&acc[SW(nd, lane)], fx[u]);
                }
            }
        }
    }
    __syncthreads();

    // ---------------- P4b: MFMA  out = [x | mean] @ W2^T + b ----------------
    const int nbase = b * 256 + w * 16;
    const int row = lane & 15, q = lane >> 4;
    int nn = nbase + row;
    size_t nrow = (size_t)((nn < N_NODES) ? nn : (N_NODES - 1));

    bf16x8 a[4];
    a[0] = *(const bf16x8*)(xh + nrow * IN_DIM + q * 8);
    a[1] = *(const bf16x8*)(xh + nrow * IN_DIM + q * 8 + 32);

    const int in_node = w * 16 + row;
    int deg = dcnt[in_node];
    float sc = deg ? INVFIX / (float)deg : 0.0f;
    bf16x8 a2, a3;
#pragma unroll
    for (int j = 0; j < 8; ++j) {
        a2[j] = (short)f2bf((float)acc[SW(in_node, q * 8 + j)] * sc);
        a3[j] = (short)f2bf((float)acc[SW(in_node, 32 + q * 8 + j)] * sc);
    }
    a[2] = a2; a[3] = a3;

    f32x4 accf[8];
#pragma unroll
    for (int ot = 0; ot < 8; ++ot) accf[ot] = (f32x4){0.f, 0.f, 0.f, 0.f};

#pragma unroll
    for (int ot = 0; ot < 8; ++ot) {
        const unsigned short* wb = &wlds[(ot * 16 + row) * WLDS + q * 8];
#pragma unroll
        for (int s = 0; s < 4; ++s) {
            bf16x8 bfrag = *(const bf16x8*)(wb + s * 32);
            accf[ot] = __builtin_amdgcn_mfma_f32_16x16x32_bf16(a[s], bfrag, accf[ot], 0, 0, 0);
        }
    }

#pragma unroll
    for (int ot = 0; ot < 8; ++ot) {
        float bias = bls[ot * 16 + row];
#pragma unroll
        for (int r = 0; r < 4; ++r) {
            int n = nbase + q * 4 + r;
            if (n < N_NODES)
                out[(size_t)n * OUT_DIM + ot * 16 + row] = accf[ot][r] + bias;
        }
    }
}

extern "C" void kernel_launch(void* const* d_in, const int* in_sizes, int n_in,
                              void* d_out, int out_size, void* d_ws, size_t ws_size,
                              hipStream_t stream) {
    const float* x  = (const float*)d_in[0];
    const int*   ei = (const int*)d_in[1];
    const float* Wl = (const float*)d_in[2];
    const float* bl = (const float*)d_in[3];
    const float* Wr = (const float*)d_in[4];
    float* out = (float*)d_out;

    // ws layout (~9.8 MB):
    int*            bar     = (int*)d_ws;                       // 8 ints (2 used)
    int*            cnt_mat = bar + 8;                          // NB*NB ints
    int*            tot     = cnt_mat + NB * NB;                // NB ints
    unsigned*       ebuf    = (unsigned*)(tot + NB);            // N_EDGES uints
    unsigned short* xh      = (unsigned short*)(ebuf + N_EDGES);// N_NODES*64 bf16

    hipMemsetAsync(bar, 0, 8 * sizeof(int), stream);            // cnt=0, gen=0
    sage_mega<<<NB, 1024, 0, stream>>>(x, ei, Wl, bl, Wr,
                                       bar, cnt_mat, tot, ebuf, xh, out);
}

// Round 13
// 75.038 us; speedup vs baseline: 2.3883x; 2.3883x over previous
//
#include <hip/hip_runtime.h>

#define N_NODES 50000
#define IN_DIM 64
#define OUT_DIM 128
#define N_EDGES 800000

#define NPART 1024                  // partition blocks (4/CU)
#define EPP 782                     // ceil(N_EDGES / NPART)
#define NBUCK 391                   // ceil(50000/128) buckets of 128 dsts
#define WLDS 136                    // padded bf16 row stride: bank step 4 -> 2-way (free)
#define FIXSCALE 1048576.0f         // 2^20 fixed-point
#define INVFIX (1.0f / 1048576.0f)

typedef __attribute__((ext_vector_type(8))) short bf16x8;
typedef __attribute__((ext_vector_type(4))) float f32x4;

__device__ __forceinline__ unsigned short f2bf(float f) {
    unsigned u = __float_as_uint(f);
    unsigned r = u + 0x7FFFu + ((u >> 16) & 1u);   // round-to-nearest-even
    return (unsigned short)(r >> 16);
}

// acc swizzle: feature f of node nd at acc[nd*64 + (f ^ ((nd&7)<<3))]
// gather write: bank permutation per node -> still 2-way (free);
// mean read (16 rows same f-group): spread over 8 banks -> ~2-way.
__device__ __forceinline__ int SW(int nd, int f) { return (nd << 6) + (f ^ ((nd & 7) << 3)); }

// ---------------- P1: per-(partition,bucket) histogram + x->bf16 + W2->bf16 ----------------
__global__ __launch_bounds__(256) void p1_count_cvt(const int* __restrict__ ei,
                                                    const float* __restrict__ x,
                                                    const float* __restrict__ Wl,
                                                    const float* __restrict__ Wr,
                                                    int* __restrict__ cnt_mat,
                                                    unsigned short* __restrict__ xh,
                                                    unsigned short* __restrict__ w2h)
{
    __shared__ int h[NBUCK];
    int t = threadIdx.x, blk = blockIdx.x;
    for (int i = t; i < NBUCK; i += 256) h[i] = 0;
    __syncthreads();
    int s = blk * EPP;
    int e_end = min(s + EPP, N_EDGES);
    for (int i = s + t; i < e_end; i += 256)
        atomicAdd(&h[ei[N_EDGES + i] >> 7], 1);
    // x -> bf16, grid-stride over 800000 float4 (≈3 iters/thread)
    for (int gi = blk * 256 + t; gi < N_NODES * 16; gi += NPART * 256) {
        float4 v = ((const float4*)x)[gi];
        ushort4 o;
        o.x = f2bf(v.x); o.y = f2bf(v.y); o.z = f2bf(v.z); o.w = f2bf(v.w);
        ((ushort4*)xh)[gi] = o;
    }
    // W2h[o] = [Wr[o] | Wl[o]] bf16 (blocks 0..127, one out-row each)
    if (blk < 128 && t < 64) {
        w2h[blk * 128 + t]      = f2bf(Wr[blk * 64 + t]);
        w2h[blk * 128 + 64 + t] = f2bf(Wl[blk * 64 + t]);
    }
    __syncthreads();
    for (int b = t; b < NBUCK; b += 256) cnt_mat[b * NPART + blk] = h[b];
}

// ---------------- rowsum: tot[b] = sum of cnt_mat row b ----------------
__global__ __launch_bounds__(256) void rowsum(const int* __restrict__ cnt_mat,
                                              int* __restrict__ tot)
{
    __shared__ int ws[4];
    int t = threadIdx.x, b = blockIdx.x;
    int lane = t & 63, w = t >> 6;
    int4 v = ((const int4*)(cnt_mat + b * NPART))[t];   // 256 x int4 = 1024 ints
    int sv = v.x + v.y + v.z + v.w;
#pragma unroll
    for (int d = 32; d >= 1; d >>= 1) sv += __shfl_down(sv, d, 64);
    if (lane == 0) ws[w] = sv;
    __syncthreads();
    if (t == 0) tot[b] = ws[0] + ws[1] + ws[2] + ws[3];
}

// ---------------- rowscan2: cursors = bucket_start + exclusive scan of row ----------------
// Each block: redundant 391-total exclusive scan (wave 0) + block-scan of its
// 1024-entry row (one int4 per thread, all loads parallel).
__global__ __launch_bounds__(256) void rowscan2(int* __restrict__ cnt_mat,
                                                const int* __restrict__ tot)
{
    __shared__ int bst_s;
    __shared__ int wtot[4];
    int t = threadIdx.x, b = blockIdx.x;
    int lane = t & 63, w = t >> 6;

    int4 mine = ((const int4*)(cnt_mat + b * NPART))[t];
    int s = mine.x + mine.y + mine.z + mine.w;
    int incl = s;
#pragma unroll
    for (int d = 1; d < 64; d <<= 1) {
        int u = __shfl_up(incl, d, 64);
        if (lane >= d) incl += u;
    }
    if (lane == 63) wtot[w] = incl;

    if (w == 0) {                       // redundant scan of bucket totals
        int carry = 0;
        for (int base = 0; base < NBUCK; base += 64) {   // 7 chunks
            int i = base + lane;
            int v = (i < NBUCK) ? tot[i] : 0;
            int ic = v;
#pragma unroll
            for (int d = 1; d < 64; d <<= 1) {
                int u = __shfl_up(ic, d, 64);
                if (lane >= d) ic += u;
            }
            if (i == b) bst_s = carry + ic - v;
            carry += __shfl(ic, 63, 64);
        }
    }
    __syncthreads();
    int woff = 0;
    for (int j = 0; j < w; ++j) woff += wtot[j];
    int base = bst_s + woff + incl - s;       // exclusive before this thread's 4
    int4 outv;
    outv.x = base;
    outv.y = base + mine.x;
    outv.z = base + mine.x + mine.y;
    outv.w = base + mine.x + mine.y + mine.z;
    ((int4*)(cnt_mat + b * NPART))[t] = outv;
}

// ---------------- place: partition edges into bucket-contiguous packed ebuf ----------------
__global__ __launch_bounds__(256) void bucket_place(const int* __restrict__ ei,
                                                    const int* __restrict__ cnt_scan,
                                                    unsigned* __restrict__ ebuf)
{
    __shared__ int cur[NBUCK];
    int t = threadIdx.x, blk = blockIdx.x;
    for (int b = t; b < NBUCK; b += 256) cur[b] = cnt_scan[b * NPART + blk];
    __syncthreads();
    int s = blk * EPP;
    int e_end = min(s + EPP, N_EDGES);
    for (int i = s + t; i < e_end; i += 256) {
        int src = ei[i], dst = ei[N_EDGES + i];
        int slot = atomicAdd(&cur[dst >> 7], 1);
        ebuf[slot] = (unsigned)src | ((unsigned)(dst & 127) << 16);
    }
}

// ---------------- fused gather (LDS int fixed-point) + MFMA linear ----------------
__global__ __launch_bounds__(1024) void gather_mfma(const unsigned short* __restrict__ xh,
                                                    const int* __restrict__ cnt_scan,
                                                    const unsigned* __restrict__ ebuf,
                                                    const unsigned short* __restrict__ w2h,
                                                    const float* __restrict__ bl,
                                                    float* __restrict__ out)
{
    __shared__ int acc[128 * 64];                 // 32 KB
    __shared__ unsigned short wlds[128 * WLDS];   // 34.8 KB
    __shared__ int dcnt[128];
    __shared__ int range_s[2];
    int t = threadIdx.x, b = blockIdx.x;
    int lane = t & 63, w = t >> 6;                // 16 waves

#pragma unroll
    for (int c = 0; c < 2; ++c) {
        int idx = c * 1024 + t;
        int o = idx >> 4, kc = idx & 15;
        bf16x8 v = *(const bf16x8*)(w2h + o * 128 + kc * 8);
        *(bf16x8*)(&wlds[o * WLDS + kc * 8]) = v;
    }
    if (t == 0) {
        range_s[0] = cnt_scan[b * NPART];
        range_s[1] = (b < NBUCK - 1) ? cnt_scan[(b + 1) * NPART] : N_EDGES;
    }
#pragma unroll
    for (int i = 0; i < 8; ++i) acc[i * 1024 + t] = 0;
    if (t < 128) dcnt[t] = 0;
    __syncthreads();

    int bs = range_s[0], be = range_s[1];

    for (int e = bs + t; e < be; e += 1024)
        atomicAdd(&dcnt[(ebuf[e] >> 16) & 127], 1);

    for (int e0 = bs + w * 64; e0 < be; e0 += 1024) {
        int m = be - e0; if (m > 64) m = 64;
        unsigned pv = (lane < m) ? ebuf[e0 + lane] : 0u;
        for (int k = 0; k < m; k += 8) {
            unsigned p[8]; int fx[8];
#pragma unroll
            for (int u = 0; u < 8; ++u) p[u] = __shfl(pv, k + u, 64);
#pragma unroll
            for (int u = 0; u < 8; ++u) {
                unsigned short hv = xh[(size_t)(p[u] & 0xFFFFu) * IN_DIM + lane];
                fx[u] = __float2int_rn(__uint_as_float((unsigned)hv << 16) * FIXSCALE);
            }
#pragma unroll
            for (int u = 0; u < 8; ++u)
                if (k + u < m)
                    atomicAdd(&acc[SW((p[u] >> 16) & 127, lane)], fx[u]);
        }
    }
    __syncthreads();

    // -------- MFMA: out = [x | mean] @ W2^T + b --------
    int s_strip = w & 7, hf = w >> 3;
    int nbase = b * 128 + s_strip * 16;
    if (nbase >= N_NODES) return;
    int row = lane & 15, q = lane >> 4;
    int nn = nbase + row;
    size_t nrow = (size_t)((nn < N_NODES) ? nn : (N_NODES - 1));

    bf16x8 a[4];
    a[0] = *(const bf16x8*)(xh + nrow * IN_DIM + q * 8);
    a[1] = *(const bf16x8*)(xh + nrow * IN_DIM + q * 8 + 32);

    int in_node = s_strip * 16 + row;
    int deg = dcnt[in_node];
    float sc = deg ? INVFIX / (float)deg : 0.0f;
    bf16x8 a2, a3;
#pragma unroll
    for (int j = 0; j < 8; ++j) {
        a2[j] = (short)f2bf((float)acc[SW(in_node, q * 8 + j)] * sc);
        a3[j] = (short)f2bf((float)acc[SW(in_node, 32 + q * 8 + j)] * sc);
    }
    a[2] = a2; a[3] = a3;

    f32x4 accf[4];
#pragma unroll
    for (int jj = 0; jj < 4; ++jj) accf[jj] = (f32x4){0.f, 0.f, 0.f, 0.f};

#pragma unroll
    for (int jj = 0; jj < 4; ++jj) {
        int ot = hf * 4 + jj;
        const unsigned short* wb = &wlds[(ot * 16 + row) * WLDS + q * 8];
#pragma unroll
        for (int s = 0; s < 4; ++s) {
            bf16x8 bfrag = *(const bf16x8*)(wb + s * 32);
            accf[jj] = __builtin_amdgcn_mfma_f32_16x16x32_bf16(a[s], bfrag, accf[jj], 0, 0, 0);
        }
    }

#pragma unroll
    for (int jj = 0; jj < 4; ++jj) {
        int ot = hf * 4 + jj;
        float bias = bl[ot * 16 + row];
#pragma unroll
        for (int r = 0; r < 4; ++r) {
            int n = nbase + q * 4 + r;
            if (n < N_NODES)
                out[(size_t)n * OUT_DIM + ot * 16 + row] = accf[jj][r] + bias;
        }
    }
}

extern "C" void kernel_launch(void* const* d_in, const int* in_sizes, int n_in,
                              void* d_out, int out_size, void* d_ws, size_t ws_size,
                              hipStream_t stream) {
    const float* x  = (const float*)d_in[0];
    const int*   ei = (const int*)d_in[1];
    const float* Wl = (const float*)d_in[2];
    const float* bl = (const float*)d_in[3];
    const float* Wr = (const float*)d_in[4];
    float* out = (float*)d_out;

    // ws layout (~11.3 MB):
    int*            cnt_mat = (int*)d_ws;                               // 391*1024 ints
    int*            tot     = cnt_mat + NBUCK * NPART;                  // 391 ints
    unsigned*       ebuf    = (unsigned*)(tot + NBUCK + 1);             // 800000 uints
    unsigned short* xh      = (unsigned short*)(ebuf + N_EDGES);        // 3.2M bf16
    unsigned short* w2h     = xh + (size_t)N_NODES * IN_DIM;            // 16384 bf16

    p1_count_cvt<<<NPART, 256, 0, stream>>>(ei, x, Wl, Wr, cnt_mat, xh, w2h);
    rowsum<<<NBUCK, 256, 0, stream>>>(cnt_mat, tot);
    rowscan2<<<NBUCK, 256, 0, stream>>>(cnt_mat, tot);
    bucket_place<<<NPART, 256, 0, stream>>>(ei, cnt_mat, ebuf);
    gather_mfma<<<NBUCK, 1024, 0, stream>>>(xh, cnt_mat, ebuf, w2h, bl, out);
}

// Round 14
// 73.826 us; speedup vs baseline: 2.4275x; 1.0164x over previous
//
#include <hip/hip_runtime.h>

#define N_NODES 50000
#define IN_DIM 64
#define OUT_DIM 128
#define N_EDGES 800000

#define NPART 1024                  // histogram partitions
#define EPP 782                     // ceil(N_EDGES / NPART)
#define NPLACE 256                  // place blocks (4 hist partitions each)
#define NBUCK 391                   // ceil(50000/128) buckets of 128 dsts
#define WLDS 136                    // padded bf16 row stride: bank step 4 -> 2-way (free)
#define FIXSCALE 1048576.0f         // 2^20 fixed-point
#define INVFIX (1.0f / 1048576.0f)

typedef __attribute__((ext_vector_type(8))) short bf16x8;
typedef __attribute__((ext_vector_type(4))) float f32x4;

__device__ __forceinline__ unsigned short f2bf(float f) {
    unsigned u = __float_as_uint(f);
    unsigned r = u + 0x7FFFu + ((u >> 16) & 1u);   // round-to-nearest-even
    return (unsigned short)(r >> 16);
}

// acc swizzle: feature f of node nd at acc[nd*64 + (f ^ ((nd&7)<<3))]
__device__ __forceinline__ int SW(int nd, int f) { return (nd << 6) + (f ^ ((nd & 7) << 3)); }

// ---------------- P1: per-(partition,bucket) histogram + x->bf16 + W2->bf16 ----------------
__global__ __launch_bounds__(256) void p1_count_cvt(const int* __restrict__ ei,
                                                    const float* __restrict__ x,
                                                    const float* __restrict__ Wl,
                                                    const float* __restrict__ Wr,
                                                    int* __restrict__ cnt_mat,
                                                    unsigned short* __restrict__ xh,
                                                    unsigned short* __restrict__ w2h)
{
    __shared__ int h[NBUCK];
    int t = threadIdx.x, blk = blockIdx.x;
    for (int i = t; i < NBUCK; i += 256) h[i] = 0;
    __syncthreads();
    int s = blk * EPP;
    int e_end = min(s + EPP, N_EDGES);
    for (int i = s + t; i < e_end; i += 256)
        atomicAdd(&h[ei[N_EDGES + i] >> 7], 1);
    // x -> bf16, grid-stride over 800000 float4 (~3 iters/thread)
    for (int gi = blk * 256 + t; gi < N_NODES * 16; gi += NPART * 256) {
        float4 v = ((const float4*)x)[gi];
        ushort4 o;
        o.x = f2bf(v.x); o.y = f2bf(v.y); o.z = f2bf(v.z); o.w = f2bf(v.w);
        ((ushort4*)xh)[gi] = o;
    }
    // W2h[o] = [Wr[o] | Wl[o]] bf16 (blocks 0..127, one out-row each)
    if (blk < 128 && t < 64) {
        w2h[blk * 128 + t]      = f2bf(Wr[blk * 64 + t]);
        w2h[blk * 128 + 64 + t] = f2bf(Wl[blk * 64 + t]);
    }
    __syncthreads();
    for (int b = t; b < NBUCK; b += 256) cnt_mat[b * NPART + blk] = h[b];
}

// ---------------- rowsum: tot[b] = sum of cnt_mat row b ----------------
__global__ __launch_bounds__(256) void rowsum(const int* __restrict__ cnt_mat,
                                              int* __restrict__ tot)
{
    __shared__ int ws[4];
    int t = threadIdx.x, b = blockIdx.x;
    int lane = t & 63, w = t >> 6;
    int4 v = ((const int4*)(cnt_mat + b * NPART))[t];   // 256 x int4 = 1024 ints
    int sv = v.x + v.y + v.z + v.w;
#pragma unroll
    for (int d = 32; d >= 1; d >>= 1) sv += __shfl_down(sv, d, 64);
    if (lane == 0) ws[w] = sv;
    __syncthreads();
    if (t == 0) tot[b] = ws[0] + ws[1] + ws[2] + ws[3];
}

// ---------------- rowscan2: cursors = bucket_start + exclusive scan of row ----------------
__global__ __launch_bounds__(256) void rowscan2(int* __restrict__ cnt_mat,
                                                const int* __restrict__ tot)
{
    __shared__ int bst_s;
    __shared__ int wtot[4];
    int t = threadIdx.x, b = blockIdx.x;
    int lane = t & 63, w = t >> 6;

    int4 mine = ((const int4*)(cnt_mat + b * NPART))[t];
    int s = mine.x + mine.y + mine.z + mine.w;
    int incl = s;
#pragma unroll
    for (int d = 1; d < 64; d <<= 1) {
        int u = __shfl_up(incl, d, 64);
        if (lane >= d) incl += u;
    }
    if (lane == 63) wtot[w] = incl;

    if (w == 0) {                       // redundant scan of bucket totals
        int carry = 0;
        for (int base = 0; base < NBUCK; base += 64) {   // 7 chunks
            int i = base + lane;
            int v = (i < NBUCK) ? tot[i] : 0;
            int ic = v;
#pragma unroll
            for (int d = 1; d < 64; d <<= 1) {
                int u = __shfl_up(ic, d, 64);
                if (lane >= d) ic += u;
            }
            if (i == b) bst_s = carry + ic - v;
            carry += __shfl(ic, 63, 64);
        }
    }
    __syncthreads();
    int woff = 0;
    for (int j = 0; j < w; ++j) woff += wtot[j];
    int base = bst_s + woff + incl - s;
    int4 outv;
    outv.x = base;
    outv.y = base + mine.x;
    outv.z = base + mine.x + mine.y;
    outv.w = base + mine.x + mine.y + mine.z;
    ((int4*)(cnt_mat + b * NPART))[t] = outv;
}

// ---------------- place: 256 blocks, each covers 4 hist partitions ----------------
// cursor for block p = cnt_scan[b][4p] (exclusive scan along row covers exactly
// partitions 4p..4p+3's edge range [4p*EPP, (4p+4)*EPP) ).
__global__ __launch_bounds__(256) void bucket_place(const int* __restrict__ ei,
                                                    const int* __restrict__ cnt_scan,
                                                    unsigned* __restrict__ ebuf)
{
    __shared__ int cur[NBUCK];
    int t = threadIdx.x, blk = blockIdx.x;
    for (int b = t; b < NBUCK; b += 256) cur[b] = cnt_scan[b * NPART + blk * 4];
    __syncthreads();
    int s = blk * 4 * EPP;
    int e_end = min(s + 4 * EPP, N_EDGES);
    for (int i = s + t; i < e_end; i += 256) {
        int src = ei[i], dst = ei[N_EDGES + i];
        int slot = atomicAdd(&cur[dst >> 7], 1);
        ebuf[slot] = (unsigned)src | ((unsigned)(dst & 127) << 16);
    }
}

// ---------------- fused gather (LDS int fixed-point, 16-deep MLP) + MFMA ----------------
__global__ __launch_bounds__(1024) void gather_mfma(const unsigned short* __restrict__ xh,
                                                    const int* __restrict__ cnt_scan,
                                                    const unsigned* __restrict__ ebuf,
                                                    const unsigned short* __restrict__ w2h,
                                                    const float* __restrict__ bl,
                                                    float* __restrict__ out)
{
    __shared__ int acc[128 * 64];                 // 32 KB
    __shared__ unsigned short wlds[128 * WLDS];   // 34.8 KB
    __shared__ int dcnt[128];
    __shared__ int range_s[2];
    int t = threadIdx.x, b = blockIdx.x;
    int lane = t & 63, w = t >> 6;                // 16 waves

#pragma unroll
    for (int c = 0; c < 2; ++c) {
        int idx = c * 1024 + t;
        int o = idx >> 4, kc = idx & 15;
        bf16x8 v = *(const bf16x8*)(w2h + o * 128 + kc * 8);
        *(bf16x8*)(&wlds[o * WLDS + kc * 8]) = v;
    }
    if (t == 0) {
        range_s[0] = cnt_scan[b * NPART];
        range_s[1] = (b < NBUCK - 1) ? cnt_scan[(b + 1) * NPART] : N_EDGES;
    }
#pragma unroll
    for (int i = 0; i < 8; ++i) acc[i * 1024 + t] = 0;
    if (t < 128) dcnt[t] = 0;
    __syncthreads();

    int bs = range_s[0], be = range_s[1];

    for (int e = bs + t; e < be; e += 1024)
        atomicAdd(&dcnt[(ebuf[e] >> 16) & 127], 1);

    // 16 outstanding 128B row loads per wave (latency amortization)
    for (int e0 = bs + w * 64; e0 < be; e0 += 1024) {
        int m = be - e0; if (m > 64) m = 64;
        unsigned pv = (lane < m) ? ebuf[e0 + lane] : 0u;
        for (int k = 0; k < m; k += 16) {
            unsigned p[16]; int fx[16];
#pragma unroll
            for (int u = 0; u < 16; ++u) p[u] = __shfl(pv, k + u, 64);
#pragma unroll
            for (int u = 0; u < 16; ++u) {
                unsigned short hv = xh[(size_t)(p[u] & 0xFFFFu) * IN_DIM + lane];
                fx[u] = __float2int_rn(__uint_as_float((unsigned)hv << 16) * FIXSCALE);
            }
#pragma unroll
            for (int u = 0; u < 16; ++u)
                if (k + u < m)
                    atomicAdd(&acc[SW((p[u] >> 16) & 127, lane)], fx[u]);
        }
    }
    __syncthreads();

    // -------- MFMA: out = [x | mean] @ W2^T + b --------
    int s_strip = w & 7, hf = w >> 3;
    int nbase = b * 128 + s_strip * 16;
    if (nbase >= N_NODES) return;
    int row = lane & 15, q = lane >> 4;
    int nn = nbase + row;
    size_t nrow = (size_t)((nn < N_NODES) ? nn : (N_NODES - 1));

    bf16x8 a[4];
    a[0] = *(const bf16x8*)(xh + nrow * IN_DIM + q * 8);
    a[1] = *(const bf16x8*)(xh + nrow * IN_DIM + q * 8 + 32);

    int in_node = s_strip * 16 + row;
    int deg = dcnt[in_node];
    float sc = deg ? INVFIX / (float)deg : 0.0f;
    bf16x8 a2, a3;
#pragma unroll
    for (int j = 0; j < 8; ++j) {
        a2[j] = (short)f2bf((float)acc[SW(in_node, q * 8 + j)] * sc);
        a3[j] = (short)f2bf((float)acc[SW(in_node, 32 + q * 8 + j)] * sc);
    }
    a[2] = a2; a[3] = a3;

    f32x4 accf[4];
#pragma unroll
    for (int jj = 0; jj < 4; ++jj) accf[jj] = (f32x4){0.f, 0.f, 0.f, 0.f};

#pragma unroll
    for (int jj = 0; jj < 4; ++jj) {
        int ot = hf * 4 + jj;
        const unsigned short* wb = &wlds[(ot * 16 + row) * WLDS + q * 8];
#pragma unroll
        for (int s = 0; s < 4; ++s) {
            bf16x8 bfrag = *(const bf16x8*)(wb + s * 32);
            accf[jj] = __builtin_amdgcn_mfma_f32_16x16x32_bf16(a[s], bfrag, accf[jj], 0, 0, 0);
        }
    }

#pragma unroll
    for (int jj = 0; jj < 4; ++jj) {
        int ot = hf * 4 + jj;
        float bias = bl[ot * 16 + row];
#pragma unroll
        for (int r = 0; r < 4; ++r) {
            int n = nbase + q * 4 + r;
            if (n < N_NODES)
                out[(size_t)n * OUT_DIM + ot * 16 + row] = accf[jj][r] + bias;
        }
    }
}

extern "C" void kernel_launch(void* const* d_in, const int* in_sizes, int n_in,
                              void* d_out, int out_size, void* d_ws, size_t ws_size,
                              hipStream_t stream) {
    const float* x  = (const float*)d_in[0];
    const int*   ei = (const int*)d_in[1];
    const float* Wl = (const float*)d_in[2];
    const float* bl = (const float*)d_in[3];
    const float* Wr = (const float*)d_in[4];
    float* out = (float*)d_out;

    // ws layout (~11.3 MB):
    int*            cnt_mat = (int*)d_ws;                               // 391*1024 ints
    int*            tot     = cnt_mat + NBUCK * NPART;                  // 391 ints
    unsigned*       ebuf    = (unsigned*)(tot + NBUCK + 1);             // 800000 uints
    unsigned short* xh      = (unsigned short*)(ebuf + N_EDGES);        // 3.2M bf16
    unsigned short* w2h     = xh + (size_t)N_NODES * IN_DIM;            // 16384 bf16

    p1_count_cvt<<<NPART, 256, 0, stream>>>(ei, x, Wl, Wr, cnt_mat, xh, w2h);
    rowsum<<<NBUCK, 256, 0, stream>>>(cnt_mat, tot);
    rowscan2<<<NBUCK, 256, 0, stream>>>(cnt_mat, tot);
    bucket_place<<<NPLACE, 256, 0, stream>>>(ei, cnt_mat, ebuf);
    gather_mfma<<<NBUCK, 1024, 0, stream>>>(xh, cnt_mat, ebuf, w2h, bl, out);
}